// Round 2
// baseline (277.084 us; speedup 1.0000x reference)
//
#include <hip/hip_runtime.h>
#include <stdint.h>

#define BATCH 32
#define CIN   128
#define HH    56
#define WW    56
#define COUT  256
#define HP    58
#define WP    58

typedef __attribute__((ext_vector_type(8))) short short8;
typedef __attribute__((ext_vector_type(4))) float floatx4;

// async global->LDS, 16B per lane; LDS dest = wave-uniform base + lane*16
#define GLOAD_LDS16(gptr, lptr)                                          \
  __builtin_amdgcn_global_load_lds(                                      \
      (const __attribute__((address_space(1))) void*)(gptr),             \
      (__attribute__((address_space(3))) void*)(lptr), 16, 0, 0)

__device__ __forceinline__ unsigned short f32_to_bf16(float f) {
  unsigned int u = __float_as_uint(f);
  u = u + 0x7fffu + ((u >> 16) & 1u);
  return (unsigned short)(u >> 16);
}
__device__ __forceinline__ unsigned int pack2(float a, float b) {
  return (unsigned int)f32_to_bf16(a) | ((unsigned int)f32_to_bf16(b) << 16);
}

// ws layout: [xp_t: BATCH*HP*WP*CIN bf16][slack 1024][wt: 9*COUT*CIN bf16]
// xp_t NHWC padded: xp_t[((b*58+i)*58+j)*128+ci] = x[b][ci][i-1][j-1] or 0.
// GEMM A-reads may overrun a row by <= 9 cols (rows w>=56 discarded in the
// epilogue); max overrun past the array end is < 1024 elems (SLACK).

__global__ void pad_transpose_kernel(const float* __restrict__ x,
                                     unsigned short* __restrict__ xpt) {
  const int blk = blockIdx.x;  // b*58 + i
  const int b = blk / HP;
  const int i = blk - b * HP;
  const int t = threadIdx.x;
  unsigned short* dst = xpt + (size_t)blk * (WP * CIN);

  if (i == 0 || i == HP - 1) {  // pure pad row: store zeros, no LDS
    const uint4 z = {0, 0, 0, 0};
    for (int idx = t; idx < 928; idx += 256)
      *(uint4*)(dst + (size_t)idx * 8) = z;
    return;
  }

  __shared__ float tile[CIN * 59];  // [ci][0..57]; col0/col57 = pad
  // zero the two pad columns only
  tile[(t >> 1) * 59 + (t & 1) * 57] = 0.0f;
  // float4 row loads: ci = t>>1, seg = t&1 covers w = seg*28 .. seg*28+27
  {
    const int ci = t >> 1;
    const int seg = t & 1;
    const float* row =
        x + (((size_t)b * CIN + ci) * HH + (i - 1)) * WW + seg * 28;
    float* trow = tile + ci * 59 + 1 + seg * 28;
#pragma unroll
    for (int q = 0; q < 7; ++q) {
      const float4 v = *(const float4*)(row + q * 4);
      trow[q * 4 + 0] = v.x;
      trow[q * 4 + 1] = v.y;
      trow[q * 4 + 2] = v.z;
      trow[q * 4 + 3] = v.w;
    }
  }
  __syncthreads();
  // pack: dst[j*128 + ci] bf16; idx -> j = idx>>4, ci0 = (idx&15)*8
  for (int idx = t; idx < 928; idx += 256) {
    const int j = idx >> 4;
    const int ci0 = (idx & 15) * 8;
    uint4 pk;
    pk.x = pack2(tile[(ci0 + 0) * 59 + j], tile[(ci0 + 1) * 59 + j]);
    pk.y = pack2(tile[(ci0 + 2) * 59 + j], tile[(ci0 + 3) * 59 + j]);
    pk.z = pack2(tile[(ci0 + 4) * 59 + j], tile[(ci0 + 5) * 59 + j]);
    pk.w = pack2(tile[(ci0 + 6) * 59 + j], tile[(ci0 + 7) * 59 + j]);
    *(uint4*)(dst + (size_t)idx * 8) = pk;
  }
}

// wt[r][co][ci] = weight[co][ci][r], bf16. 36864 uint4s, 144 blocks.
__global__ void weight_transpose_kernel(const float* __restrict__ wsrc,
                                        unsigned short* __restrict__ wt) {
  const int o8 = blockIdx.x * 256 + threadIdx.x;
  const int r = o8 >> 12;
  const int rem = o8 & 4095;
  const int co = rem >> 4;
  const int ci0 = (rem & 15) * 8;
  const float* s = wsrc + ((size_t)co * CIN + ci0) * 9 + r;
  uint4 pk;
  pk.x = pack2(s[0 * 9], s[1 * 9]);
  pk.y = pack2(s[2 * 9], s[3 * 9]);
  pk.z = pack2(s[4 * 9], s[5 * 9]);
  pk.w = pack2(s[6 * 9], s[7 * 9]);
  *(uint4*)(wt + (size_t)o8 * 8) = pk;
}

// 128x128 tile, 4 waves 2x2, 64x64/wave. LDS-port relief version:
//  - A: 32 KB ring of 4 x [128][32] slots, global_load_lds, depth-2 prefetch.
//  - B: NO LDS. Per-wave direct global->VGPR short8 loads (wt is 576 KB,
//    L2-resident), ping-pong prefetched one K=32 stage ahead (bfA/bfB).
// Ordering contract per stage kk: stageA(kk+2) issues BEFORE loadB(kk+1)
// (pinned by sched_barrier). MFMA(kk)'s register dep on B(kk) then drains
// A(kk+1) before the raw s_barrier; vmcnt(6) is a safety floor. No full
// vmcnt(0) drain anywhere in the main loop.
__global__ __launch_bounds__(256, 3) void conv_gemm_kernel(
    const unsigned short* __restrict__ xpt,
    const unsigned short* __restrict__ wt,
    const float* __restrict__ bias,
    float* __restrict__ out) {
  __shared__ __align__(16) uint32_t smem[8192];  // 32 KB: 4-ring A slots
  short* const S = (short*)smem;
  float* const ep = (float*)smem;  // epilogue alias [32][132]

  const int g = blockIdx.x;
  const int xcd = g & 7;
  const int jj = g >> 3;
  const int nt = jj & 1;
  const int mt = (jj >> 1) * 8 + xcd;  // 0..895, nt-pairs 8 apart (same XCD)
  const int b = mt / 28;
  const int h0 = (mt - b * 28) * 2;
  const int co0 = nt * 128;

  const int t = threadIdx.x;
  const int lane = t & 63;
  const int wv = t >> 6;
  const int mw = wv & 1;
  const int nw = wv >> 1;
  const int laneM = lane & 15;
  const int laneKg = lane >> 4;  // 0..3 (k-chunk group)
  const int sw = (laneM & 3) ^ ((laneM >> 2) & 3);
  const int xk = (laneKg ^ sw) * 8;  // swizzled frag k offset (A only)
  const int rowreg = laneKg * 4;

  // A staging: u = c*256+t; mm = u>>2; LDS dest chunk u (linear);
  // global k-chunk ((u&3) ^ s(mm)) so the frag read un-swizzles with xk.
  const unsigned short* ag[2];
#pragma unroll
  for (int c = 0; c < 2; ++c) {
    const int u = c * 256 + t;
    const int mm = u >> 2;
    const int smm = (mm & 3) ^ ((mm >> 2) & 3);
    const int j8 = ((u & 3) ^ smm) * 8;
    ag[c] =
        xpt + ((size_t)((b * HP + h0 + (mm >> 6)) * WP + (mm & 63))) * CIN + j8;
  }
  const int dA = wv * 512;  // wave-uniform LDS dest offset (shorts)

  // B direct: lane base = row (co0 + nw*64 + laneM), k-chunk laneKg*8.
  const unsigned short* wb =
      wt + (size_t)(co0 + nw * 64 + laneM) * CIN + laneKg * 8;

  floatx4 acc[4][4] = {};
  short8 af[4], bfA[4], bfB[4];

  auto stageA = [&](int kk) {
    const int r = kk >> 2;
    const int dh = (r * 11) >> 5;  // r/3
    const int dw = r - dh * 3;
    const int aoff = (dh * WP + dw) * CIN + (kk & 3) * 32;
    short* const base = S + (kk & 3) * 4096;  // 8 KB slot
    GLOAD_LDS16(ag[0] + aoff, base + dA);
    GLOAD_LDS16(ag[1] + aoff, base + 2048 + dA);
  };
  auto loadB = [&](int kk, short8* bf) {
    const unsigned short* p = wb + (kk >> 2) * (COUT * CIN) + (kk & 3) * 32;
#pragma unroll
    for (int ni = 0; ni < 4; ++ni)
      bf[ni] = *(const short8*)(p + ni * 16 * CIN);
  };
  auto frags = [&](int kk) {
    const short* Ab = S + (kk & 3) * 4096;
#pragma unroll
    for (int mi = 0; mi < 4; ++mi)
      af[mi] = *(const short8*)&Ab[(mw * 64 + mi * 16 + laneM) * 32 + xk];
  };
  auto mfma16 = [&](short8* bf) {
#pragma unroll
    for (int mi = 0; mi < 4; ++mi)
#pragma unroll
      for (int ni = 0; ni < 4; ++ni)
        acc[mi][ni] = __builtin_amdgcn_mfma_f32_16x16x32_bf16(
            af[mi], bf[ni], acc[mi][ni], 0, 0, 0);
  };

  // prologue: A(0),A(1) in flight; B(0) in regs; publish A(0)
  stageA(0);
  stageA(1);
  __builtin_amdgcn_sched_barrier(0);
  loadB(0, bfA);
  __builtin_amdgcn_sched_barrier(0);
  asm volatile("s_waitcnt vmcnt(6)" ::: "memory");  // A(0) landed
  __builtin_amdgcn_s_barrier();
  __builtin_amdgcn_sched_barrier(0);

  for (int k2 = 0; k2 < 18; ++k2) {
    const int kk = k2 * 2;
    const bool more = (k2 < 17);
    // even stage: consume bfA, prefetch bfB
    frags(kk);
    if (more) stageA(kk + 2);
    __builtin_amdgcn_sched_barrier(0);  // pin: A-issue before B-issue
    loadB(kk + 1, bfB);
    __builtin_amdgcn_sched_barrier(0);  // pin: B-issue before MFMA
    __builtin_amdgcn_s_setprio(1);
    mfma16(bfA);
    __builtin_amdgcn_s_setprio(0);
    asm volatile("s_waitcnt vmcnt(6)" ::: "memory");
    __builtin_amdgcn_s_barrier();  // publish A(kk+1)
    __builtin_amdgcn_sched_barrier(0);
    // odd stage: consume bfB, prefetch bfA
    frags(kk + 1);
    if (more) stageA(kk + 3);
    __builtin_amdgcn_sched_barrier(0);
    if (more) loadB(kk + 2, bfA);
    __builtin_amdgcn_sched_barrier(0);
    __builtin_amdgcn_s_setprio(1);
    mfma16(bfB);
    __builtin_amdgcn_s_setprio(0);
    if (more) {
      asm volatile("s_waitcnt vmcnt(6)" ::: "memory");
      __builtin_amdgcn_s_barrier();  // publish A(kk+2)
      __builtin_amdgcn_sched_barrier(0);
    }
  }

  // Epilogue: 4 chunks of 32co x 128m via LDS -> dense 224B row stores.
  // acc[mi][ni] lane l: m = mw*64+mi*16+(l>>4)*4+reg, co = co0+nw*64+ni*16+(l&15)
  for (int ni = 0; ni < 4; ++ni) {
    __syncthreads();
#pragma unroll
    for (int mi = 0; mi < 4; ++mi)
      *(float4*)&ep[(nw * 16 + laneM) * 132 + mw * 64 + mi * 16 + rowreg] =
          *(float4*)&acc[mi][ni];
    __syncthreads();
#pragma unroll
    for (int rr = 0; rr < 16; ++rr) {
      const int rowid = wv * 16 + rr;
      const int cg = rowid >> 1;  // 0..31: (nw<<4)|laneM of producer
      const int hh = rowid & 1;
      const int co = co0 + (cg >> 4) * 64 + ni * 16 + (cg & 15);
      const float bv = bias[co];
      if (lane < WW) {
        out[(((size_t)b * COUT + co) * HH + h0 + hh) * WW + lane] =
            ep[cg * 132 + hh * 64 + lane] + bv;
      }
    }
  }
}

// Fallback if ws is too small: correct but slow.
__global__ void naive_conv_kernel(const float* __restrict__ x,
                                  const float* __restrict__ wgt,
                                  const float* __restrict__ bias,
                                  float* __restrict__ out, long n) {
  long idx = (long)blockIdx.x * 256 + threadIdx.x;
  if (idx >= n) return;
  int w = (int)(idx % WW);
  long q = idx / WW;
  int h = (int)(q % HH);
  q /= HH;
  int co = (int)(q % COUT);
  int b = (int)(q / COUT);
  float s = bias[co];
  for (int ci = 0; ci < CIN; ++ci) {
    const float* xp = x + (((size_t)b * CIN + ci) * HH) * WW;
    const float* wp = wgt + ((size_t)co * CIN + ci) * 9;
    for (int dh = 0; dh < 3; ++dh) {
      int hh = h + dh - 1;
      if (hh < 0 || hh >= HH) continue;
      for (int dw = 0; dw < 3; ++dw) {
        int ww2 = w + dw - 1;
        if (ww2 < 0 || ww2 >= WW) continue;
        s += xp[hh * WW + ww2] * wp[dh * 3 + dw];
      }
    }
  }
  out[idx] = s;
}

extern "C" void kernel_launch(void* const* d_in, const int* in_sizes, int n_in,
                              void* d_out, int out_size, void* d_ws,
                              size_t ws_size, hipStream_t stream) {
  const float* x = (const float*)d_in[0];
  const float* wgt = (const float*)d_in[1];
  const float* bias = (const float*)d_in[2];
  float* out = (float*)d_out;

  const size_t XPT = (size_t)BATCH * HP * WP * CIN;  // 13,778,944
  const size_t SLACK = 1024;
  const size_t WT = (size_t)9 * COUT * CIN;  // 294,912
  const size_t need = (XPT + SLACK + WT) * sizeof(unsigned short);

  if (ws_size >= need) {
    unsigned short* xpt = (unsigned short*)d_ws;
    unsigned short* wtp = xpt + XPT + SLACK;
    hipLaunchKernelGGL(pad_transpose_kernel, dim3(BATCH * HP), dim3(256), 0,
                       stream, x, xpt);
    hipLaunchKernelGGL(weight_transpose_kernel, dim3(144), dim3(256), 0,
                       stream, wgt, wtp);
    hipLaunchKernelGGL(conv_gemm_kernel, dim3(896 * 2), dim3(256), 0, stream,
                       xpt, wtp, bias, out);
  } else {
    long n = (long)out_size;
    hipLaunchKernelGGL(naive_conv_kernel, dim3((unsigned)((n + 255) / 256)),
                       dim3(256), 0, stream, x, wgt, bias, out, n);
  }
}

// Round 3
// 274.264 us; speedup vs baseline: 1.0103x; 1.0103x over previous
//
#include <hip/hip_runtime.h>
#include <stdint.h>

#define BATCH 32
#define CIN   128
#define HH    56
#define WW    56
#define COUT  256
#define HP    58
#define WP    58

typedef __attribute__((ext_vector_type(8))) short short8;
typedef __attribute__((ext_vector_type(4))) float floatx4;

// async global->LDS, 16B per lane; LDS dest = wave-uniform base + lane*16
#define GLOAD_LDS16(gptr, lptr)                                          \
  __builtin_amdgcn_global_load_lds(                                      \
      (const __attribute__((address_space(1))) void*)(gptr),             \
      (__attribute__((address_space(3))) void*)(lptr), 16, 0, 0)

__device__ __forceinline__ unsigned short f32_to_bf16(float f) {
  unsigned int u = __float_as_uint(f);
  u = u + 0x7fffu + ((u >> 16) & 1u);
  return (unsigned short)(u >> 16);
}
__device__ __forceinline__ unsigned int pack2(float a, float b) {
  return (unsigned int)f32_to_bf16(a) | ((unsigned int)f32_to_bf16(b) << 16);
}

// ws layout: [xp_t: BATCH*HP*WP*CIN bf16][slack 1024][wt: 9*COUT*CIN bf16]
// xp_t NHWC padded: xp_t[((b*58+i)*58+j)*128+ci] = x[b][ci][i-1][j-1] or 0.
// GEMM A-reads may overrun a row by <= 9 cols (rows w>=56 discarded in the
// epilogue); worst-case overrun ends exactly at XPT+SLACK (checked: b=31,
// hp=57, w=65 -> last elem index 13,779,967 < 13,779,968).

__global__ void pad_transpose_kernel(const float* __restrict__ x,
                                     unsigned short* __restrict__ xpt) {
  const int blk = blockIdx.x;  // b*58 + i
  const int b = blk / HP;
  const int i = blk - b * HP;
  const int t = threadIdx.x;
  unsigned short* dst = xpt + (size_t)blk * (WP * CIN);

  if (i == 0 || i == HP - 1) {  // pure pad row: store zeros, no LDS
    const uint4 z = {0, 0, 0, 0};
    for (int idx = t; idx < 928; idx += 256)
      *(uint4*)(dst + (size_t)idx * 8) = z;
    return;
  }

  __shared__ float tile[CIN * 59];  // [ci][0..57]; col0/col57 = pad
  // zero the two pad columns only
  tile[(t >> 1) * 59 + (t & 1) * 57] = 0.0f;
  // float4 row loads: ci = t>>1, seg = t&1 covers w = seg*28 .. seg*28+27
  {
    const int ci = t >> 1;
    const int seg = t & 1;
    const float* row =
        x + (((size_t)b * CIN + ci) * HH + (i - 1)) * WW + seg * 28;
    float* trow = tile + ci * 59 + 1 + seg * 28;
#pragma unroll
    for (int q = 0; q < 7; ++q) {
      const float4 v = *(const float4*)(row + q * 4);
      trow[q * 4 + 0] = v.x;
      trow[q * 4 + 1] = v.y;
      trow[q * 4 + 2] = v.z;
      trow[q * 4 + 3] = v.w;
    }
  }
  __syncthreads();
  // pack: dst[j*128 + ci] bf16; idx -> j = idx>>4, ci0 = (idx&15)*8
  for (int idx = t; idx < 928; idx += 256) {
    const int j = idx >> 4;
    const int ci0 = (idx & 15) * 8;
    uint4 pk;
    pk.x = pack2(tile[(ci0 + 0) * 59 + j], tile[(ci0 + 1) * 59 + j]);
    pk.y = pack2(tile[(ci0 + 2) * 59 + j], tile[(ci0 + 3) * 59 + j]);
    pk.z = pack2(tile[(ci0 + 4) * 59 + j], tile[(ci0 + 5) * 59 + j]);
    pk.w = pack2(tile[(ci0 + 6) * 59 + j], tile[(ci0 + 7) * 59 + j]);
    *(uint4*)(dst + (size_t)idx * 8) = pk;
  }
}

// wt[r][co][ci] = weight[co][ci][r], bf16. 36864 uint4s, 144 blocks.
__global__ void weight_transpose_kernel(const float* __restrict__ wsrc,
                                        unsigned short* __restrict__ wt) {
  const int o8 = blockIdx.x * 256 + threadIdx.x;
  const int r = o8 >> 12;
  const int rem = o8 & 4095;
  const int co = rem >> 4;
  const int ci0 = (rem & 15) * 8;
  const float* s = wsrc + ((size_t)co * CIN + ci0) * 9 + r;
  uint4 pk;
  pk.x = pack2(s[0 * 9], s[1 * 9]);
  pk.y = pack2(s[2 * 9], s[3 * 9]);
  pk.z = pack2(s[4 * 9], s[5 * 9]);
  pk.w = pack2(s[6 * 9], s[7 * 9]);
  *(uint4*)(wt + (size_t)o8 * 8) = pk;
}

// 256x256 tile, 8 waves (2M x 4N), 128x64 out/wave, 512 threads.
// K = 1152 processed as 36 stages of K=32 through a ring of 4 LDS slots
// (32 KB each: A[256][32] + B[256][32]), depth-3 prefetch via
// global_load_lds, counted s_waitcnt vmcnt(8) mid-loop (never 0),
// one raw s_barrier per stage, setprio around the 32-MFMA cluster.
// Linear LDS layout (no swizzle: b128 read cost is structural, measured
// invariant to swizzle across rounds 0-2). Grid 448 = 32 b x 14 hq;
// each block covers 4 h-rows x 64 w (w>=56 garbage, dropped in epilogue).
__global__ __launch_bounds__(512, 2) void conv_gemm_kernel(
    const unsigned short* __restrict__ xpt,
    const unsigned short* __restrict__ wt,
    const float* __restrict__ bias,
    float* __restrict__ out) {
  __shared__ __align__(16) uint32_t smem[32768];  // 128 KB: 4-slot ring
  short* const S = (short*)smem;
  float* const ep = (float*)smem;  // epilogue alias [64 co'][260]

  // bijective XCD chunking: 448 % 8 == 0, each XCD gets 56 contiguous mt
  const int g = blockIdx.x;
  const int mt = (g & 7) * 56 + (g >> 3);  // 0..447
  const int b = mt / 14;
  const int h0 = (mt - b * 14) * 4;

  const int t = threadIdx.x;
  const int lane = t & 63;
  const int wv = t >> 6;      // 0..7
  const int mw = wv >> 2;     // 0..1
  const int nw = wv & 3;      // 0..3
  const int laneM = lane & 15;
  const int laneKg = lane >> 4;     // 0..3 (k-chunk group)
  const int rowreg = laneKg * 4;

  // staging sources: chunk u = c*512 + t; mm = u>>2 (row), p = u&3 (k-chunk)
  const unsigned short* ag[2];
  const unsigned short* bg[2];
#pragma unroll
  for (int c = 0; c < 2; ++c) {
    const int u = c * 512 + t;
    const int mm = u >> 2;
    const int p = u & 3;
    ag[c] = xpt +
            ((size_t)((b * HP + h0 + (mm >> 6)) * WP + (mm & 63))) * CIN +
            p * 8;
    bg[c] = wt + (size_t)mm * CIN + p * 8;  // co = mm, tap offset added later
  }
  const int dW = wv * 512;  // wave-uniform LDS dest offset (shorts)

  floatx4 acc[8][4] = {};

  // stage kk: r = kk>>2 (tap), ci0 = (kk&3)*32; 4 gload_lds per thread
  auto stageK = [&](int kk) {
    const int r = kk >> 2;
    const int dh = (r * 11) >> 5;  // r/3
    const int dw = r - dh * 3;
    const int aoff = (dh * WP + dw) * CIN + (kk & 3) * 32;
    const int boff = r * (COUT * CIN) + (kk & 3) * 32;
    short* const slot = S + (kk & 3) * 16384;  // 32 KB slot
    GLOAD_LDS16(ag[0] + aoff, slot + dW);
    GLOAD_LDS16(ag[1] + aoff, slot + 4096 + dW);
    GLOAD_LDS16(bg[0] + boff, slot + 8192 + dW);
    GLOAD_LDS16(bg[1] + boff, slot + 12288 + dW);
  };

  // prologue: stages 0..2 in flight (12 ops); publish stage 0
  stageK(0);
  stageK(1);
  stageK(2);
  __builtin_amdgcn_sched_barrier(0);
  asm volatile("s_waitcnt vmcnt(8)" ::: "memory");
  __builtin_amdgcn_s_barrier();
  __builtin_amdgcn_sched_barrier(0);

  for (int kk = 0; kk < 36; ++kk) {
    const short* slot = S + (kk & 3) * 16384;
    short8 af[8], bf[4];
#pragma unroll
    for (int mi = 0; mi < 8; ++mi)
      af[mi] =
          *(const short8*)&slot[(mw * 128 + mi * 16 + laneM) * 32 + laneKg * 8];
#pragma unroll
    for (int ni = 0; ni < 4; ++ni)
      bf[ni] = *(const short8*)&slot[8192 +
                                     (nw * 64 + ni * 16 + laneM) * 32 +
                                     laneKg * 8];
    if (kk <= 32) stageK(kk + 3);  // depth-3 prefetch into slot (kk+3)&3
    __builtin_amdgcn_sched_barrier(0);
    __builtin_amdgcn_s_setprio(1);
#pragma unroll
    for (int mi = 0; mi < 8; ++mi)
#pragma unroll
      for (int ni = 0; ni < 4; ++ni)
        acc[mi][ni] = __builtin_amdgcn_mfma_f32_16x16x32_bf16(
            af[mi], bf[ni], acc[mi][ni], 0, 0, 0);
    __builtin_amdgcn_s_setprio(0);
    // publish stage kk+1: leave deeper prefetches in flight (counted waits)
    if (kk <= 32)
      asm volatile("s_waitcnt vmcnt(8)" ::: "memory");
    else if (kk == 33)
      asm volatile("s_waitcnt vmcnt(4)" ::: "memory");
    else if (kk == 34)
      asm volatile("s_waitcnt vmcnt(0)" ::: "memory");
    if (kk < 35) {
      __builtin_amdgcn_s_barrier();
      __builtin_amdgcn_sched_barrier(0);
    }
  }

  // Epilogue: 4 chunks (ni) of 64 co' x 256 m via LDS -> 224B row stores.
  // acc[mi][ni] lane l: m = mw*128+mi*16+(l>>4)*4+reg,
  //                     co = nw*64+ni*16+(l&15)
  for (int ni = 0; ni < 4; ++ni) {
    __syncthreads();
#pragma unroll
    for (int mi = 0; mi < 8; ++mi)
      *(float4*)&ep[(nw * 16 + laneM) * 260 + mw * 128 + mi * 16 + rowreg] =
          *(float4*)&acc[mi][ni];
    __syncthreads();
#pragma unroll
    for (int rr = 0; rr < 32; ++rr) {
      const int rid = wv * 32 + rr;
      const int cp = rid >> 2;    // co' = (nw<<4)|laneM of producer
      const int hq2 = rid & 3;    // h offset within tile
      const int co = (cp >> 4) * 64 + ni * 16 + (cp & 15);
      const float bv = bias[co];
      if (lane < WW) {
        out[(((size_t)b * COUT + co) * HH + h0 + hq2) * WW + lane] =
            ep[cp * 260 + hq2 * 64 + lane] + bv;
      }
    }
  }
}

// Fallback if ws is too small: correct but slow.
__global__ void naive_conv_kernel(const float* __restrict__ x,
                                  const float* __restrict__ wgt,
                                  const float* __restrict__ bias,
                                  float* __restrict__ out, long n) {
  long idx = (long)blockIdx.x * 256 + threadIdx.x;
  if (idx >= n) return;
  int w = (int)(idx % WW);
  long q = idx / WW;
  int h = (int)(q % HH);
  q /= HH;
  int co = (int)(q % COUT);
  int b = (int)(q / COUT);
  float s = bias[co];
  for (int ci = 0; ci < CIN; ++ci) {
    const float* xp = x + (((size_t)b * CIN + ci) * HH) * WW;
    const float* wp = wgt + ((size_t)co * CIN + ci) * 9;
    for (int dh = 0; dh < 3; ++dh) {
      int hh = h + dh - 1;
      if (hh < 0 || hh >= HH) continue;
      for (int dw = 0; dw < 3; ++dw) {
        int ww2 = w + dw - 1;
        if (ww2 < 0 || ww2 >= WW) continue;
        s += xp[hh * WW + ww2] * wp[dh * 3 + dw];
      }
    }
  }
  out[idx] = s;
}

extern "C" void kernel_launch(void* const* d_in, const int* in_sizes, int n_in,
                              void* d_out, int out_size, void* d_ws,
                              size_t ws_size, hipStream_t stream) {
  const float* x = (const float*)d_in[0];
  const float* wgt = (const float*)d_in[1];
  const float* bias = (const float*)d_in[2];
  float* out = (float*)d_out;

  const size_t XPT = (size_t)BATCH * HP * WP * CIN;  // 13,778,944
  const size_t SLACK = 1024;
  const size_t WT = (size_t)9 * COUT * CIN;  // 294,912
  const size_t need = (XPT + SLACK + WT) * sizeof(unsigned short);

  if (ws_size >= need) {
    unsigned short* xpt = (unsigned short*)d_ws;
    unsigned short* wtp = xpt + XPT + SLACK;
    hipLaunchKernelGGL(pad_transpose_kernel, dim3(BATCH * HP), dim3(256), 0,
                       stream, x, xpt);
    hipLaunchKernelGGL(weight_transpose_kernel, dim3(144), dim3(256), 0,
                       stream, wgt, wtp);
    hipLaunchKernelGGL(conv_gemm_kernel, dim3(448), dim3(512), 0, stream,
                       xpt, wtp, bias, out);
  } else {
    long n = (long)out_size;
    hipLaunchKernelGGL(naive_conv_kernel, dim3((unsigned)((n + 255) / 256)),
                       dim3(256), 0, stream, x, wgt, bias, out, n);
  }
}

// Round 4
// 215.412 us; speedup vs baseline: 1.2863x; 1.2732x over previous
//
#include <hip/hip_runtime.h>
#include <stdint.h>

#define BATCH 32
#define CIN   128
#define HH    56
#define WW    56
#define COUT  256
#define HP    58
#define WP    58

typedef __attribute__((ext_vector_type(8))) short short8;
typedef __attribute__((ext_vector_type(4))) float floatx4;

// async global->LDS, 16B per lane; LDS dest = wave-uniform base + lane*16
#define GLOAD_LDS16(gptr, lptr)                                          \
  __builtin_amdgcn_global_load_lds(                                      \
      (const __attribute__((address_space(1))) void*)(gptr),             \
      (__attribute__((address_space(3))) void*)(lptr), 16, 0, 0)

__device__ __forceinline__ unsigned short f32_to_bf16(float f) {
  unsigned int u = __float_as_uint(f);
  u = u + 0x7fffu + ((u >> 16) & 1u);
  return (unsigned short)(u >> 16);
}
__device__ __forceinline__ unsigned int pack2(float a, float b) {
  return (unsigned int)f32_to_bf16(a) | ((unsigned int)f32_to_bf16(b) << 16);
}

// ws layout: [xp_t: BATCH*HP*WP*CIN bf16][slack 1024][wt: 9*COUT*CIN bf16]
// xp_t NHWC padded: xp_t[((b*58+i)*58+j)*128+ci] = x[b][ci][i-1][j-1] or 0.
// GEMM A-reads may overrun a row by <= 9 cols (rows w>=56 discarded in the
// epilogue); worst-case overrun ends exactly at XPT+SLACK (checked: b=31,
// hp=57, w=65 -> last elem index 13,779,967 < 13,779,968).

__global__ void pad_transpose_kernel(const float* __restrict__ x,
                                     unsigned short* __restrict__ xpt) {
  const int blk = blockIdx.x;  // b*58 + i
  const int b = blk / HP;
  const int i = blk - b * HP;
  const int t = threadIdx.x;
  unsigned short* dst = xpt + (size_t)blk * (WP * CIN);

  if (i == 0 || i == HP - 1) {  // pure pad row: store zeros, no LDS
    const uint4 z = {0, 0, 0, 0};
    for (int idx = t; idx < 928; idx += 256)
      *(uint4*)(dst + (size_t)idx * 8) = z;
    return;
  }

  __shared__ float tile[CIN * 59];  // [ci][0..57]; col0/col57 = pad
  // zero the two pad columns only
  tile[(t >> 1) * 59 + (t & 1) * 57] = 0.0f;
  // float4 row loads: ci = t>>1, seg = t&1 covers w = seg*28 .. seg*28+27
  {
    const int ci = t >> 1;
    const int seg = t & 1;
    const float* row =
        x + (((size_t)b * CIN + ci) * HH + (i - 1)) * WW + seg * 28;
    float* trow = tile + ci * 59 + 1 + seg * 28;
#pragma unroll
    for (int q = 0; q < 7; ++q) {
      const float4 v = *(const float4*)(row + q * 4);
      trow[q * 4 + 0] = v.x;
      trow[q * 4 + 1] = v.y;
      trow[q * 4 + 2] = v.z;
      trow[q * 4 + 3] = v.w;
    }
  }
  __syncthreads();
  // pack: dst[j*128 + ci] bf16; idx -> j = idx>>4, ci0 = (idx&15)*8
  for (int idx = t; idx < 928; idx += 256) {
    const int j = idx >> 4;
    const int ci0 = (idx & 15) * 8;
    uint4 pk;
    pk.x = pack2(tile[(ci0 + 0) * 59 + j], tile[(ci0 + 1) * 59 + j]);
    pk.y = pack2(tile[(ci0 + 2) * 59 + j], tile[(ci0 + 3) * 59 + j]);
    pk.z = pack2(tile[(ci0 + 4) * 59 + j], tile[(ci0 + 5) * 59 + j]);
    pk.w = pack2(tile[(ci0 + 6) * 59 + j], tile[(ci0 + 7) * 59 + j]);
    *(uint4*)(dst + (size_t)idx * 8) = pk;
  }
}

// wt[r][co][ci] = weight[co][ci][r], bf16. 36864 uint4s, 144 blocks.
__global__ void weight_transpose_kernel(const float* __restrict__ wsrc,
                                        unsigned short* __restrict__ wt) {
  const int o8 = blockIdx.x * 256 + threadIdx.x;
  const int r = o8 >> 12;
  const int rem = o8 & 4095;
  const int co = rem >> 4;
  const int ci0 = (rem & 15) * 8;
  const float* s = wsrc + ((size_t)co * CIN + ci0) * 9 + r;
  uint4 pk;
  pk.x = pack2(s[0 * 9], s[1 * 9]);
  pk.y = pack2(s[2 * 9], s[3 * 9]);
  pk.z = pack2(s[4 * 9], s[5 * 9]);
  pk.w = pack2(s[6 * 9], s[7 * 9]);
  *(uint4*)(wt + (size_t)o8 * 8) = pk;
}

// 256x256 tile, 8 waves (2M x 4N), 128x64 out/wave, 512 threads.
// K = 1152 processed as 36 stages of K=32 through a ring of 4 LDS slots
// (32 KB each: A[256][32] + B[256][32]), depth-3 prefetch via
// global_load_lds, counted s_waitcnt vmcnt(8) mid-loop (never 0),
// one raw s_barrier per stage, setprio around the 32-MFMA cluster.
// NOTE (round-3 post-mortem): the epilogue ni loop MUST be #pragma unroll
// so acc[][] indexing is compile-time static; runtime-indexed ext_vector
// arrays go to scratch (rule #20) -> 235 MB of spill traffic, L2 thrash.
__global__ __launch_bounds__(512, 2) void conv_gemm_kernel(
    const unsigned short* __restrict__ xpt,
    const unsigned short* __restrict__ wt,
    const float* __restrict__ bias,
    float* __restrict__ out) {
  __shared__ __align__(16) uint32_t smem[32768];  // 128 KB: 4-slot ring
  short* const S = (short*)smem;
  float* const ep = (float*)smem;  // epilogue alias [64 co'][260]

  // bijective XCD chunking: 448 % 8 == 0, each XCD gets 56 contiguous mt
  const int g = blockIdx.x;
  const int mt = (g & 7) * 56 + (g >> 3);  // 0..447
  const int b = mt / 14;
  const int h0 = (mt - b * 14) * 4;

  const int t = threadIdx.x;
  const int lane = t & 63;
  const int wv = t >> 6;      // 0..7
  const int mw = wv >> 2;     // 0..1
  const int nw = wv & 3;      // 0..3
  const int laneM = lane & 15;
  const int laneKg = lane >> 4;     // 0..3 (k-chunk group)
  const int rowreg = laneKg * 4;

  // staging sources: chunk u = c*512 + t; mm = u>>2 (row), p = u&3 (k-chunk)
  const unsigned short* ag[2];
  const unsigned short* bg[2];
#pragma unroll
  for (int c = 0; c < 2; ++c) {
    const int u = c * 512 + t;
    const int mm = u >> 2;
    const int p = u & 3;
    ag[c] = xpt +
            ((size_t)((b * HP + h0 + (mm >> 6)) * WP + (mm & 63))) * CIN +
            p * 8;
    bg[c] = wt + (size_t)mm * CIN + p * 8;  // co = mm, tap offset added later
  }
  const int dW = wv * 512;  // wave-uniform LDS dest offset (shorts)

  floatx4 acc[8][4] = {};

  // stage kk: r = kk>>2 (tap), ci0 = (kk&3)*32; 4 gload_lds per thread
  auto stageK = [&](int kk) {
    const int r = kk >> 2;
    const int dh = (r * 11) >> 5;  // r/3
    const int dw = r - dh * 3;
    const int aoff = (dh * WP + dw) * CIN + (kk & 3) * 32;
    const int boff = r * (COUT * CIN) + (kk & 3) * 32;
    short* const slot = S + (kk & 3) * 16384;  // 32 KB slot
    GLOAD_LDS16(ag[0] + aoff, slot + dW);
    GLOAD_LDS16(ag[1] + aoff, slot + 4096 + dW);
    GLOAD_LDS16(bg[0] + boff, slot + 8192 + dW);
    GLOAD_LDS16(bg[1] + boff, slot + 12288 + dW);
  };

  // prologue: stages 0..2 in flight (12 ops); publish stage 0
  stageK(0);
  stageK(1);
  stageK(2);
  __builtin_amdgcn_sched_barrier(0);
  asm volatile("s_waitcnt vmcnt(8)" ::: "memory");
  __builtin_amdgcn_s_barrier();
  __builtin_amdgcn_sched_barrier(0);

  for (int kk = 0; kk < 36; ++kk) {
    const short* slot = S + (kk & 3) * 16384;
    short8 af[8], bf[4];
#pragma unroll
    for (int mi = 0; mi < 8; ++mi)
      af[mi] =
          *(const short8*)&slot[(mw * 128 + mi * 16 + laneM) * 32 + laneKg * 8];
#pragma unroll
    for (int ni = 0; ni < 4; ++ni)
      bf[ni] = *(const short8*)&slot[8192 +
                                     (nw * 64 + ni * 16 + laneM) * 32 +
                                     laneKg * 8];
    if (kk <= 32) stageK(kk + 3);  // depth-3 prefetch into slot (kk+3)&3
    __builtin_amdgcn_sched_barrier(0);
    __builtin_amdgcn_s_setprio(1);
#pragma unroll
    for (int mi = 0; mi < 8; ++mi)
#pragma unroll
      for (int ni = 0; ni < 4; ++ni)
        acc[mi][ni] = __builtin_amdgcn_mfma_f32_16x16x32_bf16(
            af[mi], bf[ni], acc[mi][ni], 0, 0, 0);
    __builtin_amdgcn_s_setprio(0);
    // publish stage kk+1: leave deeper prefetches in flight (counted waits)
    if (kk <= 32)
      asm volatile("s_waitcnt vmcnt(8)" ::: "memory");
    else if (kk == 33)
      asm volatile("s_waitcnt vmcnt(4)" ::: "memory");
    else if (kk == 34)
      asm volatile("s_waitcnt vmcnt(0)" ::: "memory");
    if (kk < 35) {
      __builtin_amdgcn_s_barrier();
      __builtin_amdgcn_sched_barrier(0);
    }
  }

  // Epilogue: 4 chunks (ni) of 64 co' x 256 m via LDS -> 224B row stores.
  // acc[mi][ni] lane l: m = mw*128+mi*16+(l>>4)*4+reg,
  //                     co = nw*64+ni*16+(l&15)
  // ni loop MUST be unrolled: static acc indexing (rule #20, see header).
#pragma unroll
  for (int ni = 0; ni < 4; ++ni) {
    __syncthreads();
#pragma unroll
    for (int mi = 0; mi < 8; ++mi)
      *(float4*)&ep[(nw * 16 + laneM) * 260 + mw * 128 + mi * 16 + rowreg] =
          *(float4*)&acc[mi][ni];
    __syncthreads();
#pragma unroll
    for (int rr = 0; rr < 32; ++rr) {
      const int rid = wv * 32 + rr;
      const int cp = rid >> 2;    // co' = (nw<<4)|laneM of producer
      const int hq2 = rid & 3;    // h offset within tile
      const int co = (cp >> 4) * 64 + ni * 16 + (cp & 15);
      const float bv = bias[co];
      if (lane < WW) {
        out[(((size_t)b * COUT + co) * HH + h0 + hq2) * WW + lane] =
            ep[cp * 260 + hq2 * 64 + lane] + bv;
      }
    }
  }
}

// Fallback if ws is too small: correct but slow.
__global__ void naive_conv_kernel(const float* __restrict__ x,
                                  const float* __restrict__ wgt,
                                  const float* __restrict__ bias,
                                  float* __restrict__ out, long n) {
  long idx = (long)blockIdx.x * 256 + threadIdx.x;
  if (idx >= n) return;
  int w = (int)(idx % WW);
  long q = idx / WW;
  int h = (int)(q % HH);
  q /= HH;
  int co = (int)(q % COUT);
  int b = (int)(q / COUT);
  float s = bias[co];
  for (int ci = 0; ci < CIN; ++ci) {
    const float* xp = x + (((size_t)b * CIN + ci) * HH) * WW;
    const float* wp = wgt + ((size_t)co * CIN + ci) * 9;
    for (int dh = 0; dh < 3; ++dh) {
      int hh = h + dh - 1;
      if (hh < 0 || hh >= HH) continue;
      for (int dw = 0; dw < 3; ++dw) {
        int ww2 = w + dw - 1;
        if (ww2 < 0 || ww2 >= WW) continue;
        s += xp[hh * WW + ww2] * wp[dh * 3 + dw];
      }
    }
  }
  out[idx] = s;
}

extern "C" void kernel_launch(void* const* d_in, const int* in_sizes, int n_in,
                              void* d_out, int out_size, void* d_ws,
                              size_t ws_size, hipStream_t stream) {
  const float* x = (const float*)d_in[0];
  const float* wgt = (const float*)d_in[1];
  const float* bias = (const float*)d_in[2];
  float* out = (float*)d_out;

  const size_t XPT = (size_t)BATCH * HP * WP * CIN;  // 13,778,944
  const size_t SLACK = 1024;
  const size_t WT = (size_t)9 * COUT * CIN;  // 294,912
  const size_t need = (XPT + SLACK + WT) * sizeof(unsigned short);

  if (ws_size >= need) {
    unsigned short* xpt = (unsigned short*)d_ws;
    unsigned short* wtp = xpt + XPT + SLACK;
    hipLaunchKernelGGL(pad_transpose_kernel, dim3(BATCH * HP), dim3(256), 0,
                       stream, x, xpt);
    hipLaunchKernelGGL(weight_transpose_kernel, dim3(144), dim3(256), 0,
                       stream, wgt, wtp);
    hipLaunchKernelGGL(conv_gemm_kernel, dim3(448), dim3(512), 0, stream,
                       xpt, wtp, bias, out);
  } else {
    long n = (long)out_size;
    hipLaunchKernelGGL(naive_conv_kernel, dim3((unsigned)((n + 255) / 256)),
                       dim3(256), 0, stream, x, wgt, bias, out, n);
  }
}

// Round 5
// 212.212 us; speedup vs baseline: 1.3057x; 1.0151x over previous
//
#include <hip/hip_runtime.h>
#include <stdint.h>

#define BATCH 32
#define CIN   128
#define HH    56
#define WW    56
#define COUT  256
#define HP    58
#define WP    58

typedef __attribute__((ext_vector_type(8))) short short8;
typedef __attribute__((ext_vector_type(4))) float floatx4;

// async global->LDS, 16B per lane; LDS dest = wave-uniform base + lane*16
#define GLOAD_LDS16(gptr, lptr)                                          \
  __builtin_amdgcn_global_load_lds(                                      \
      (const __attribute__((address_space(1))) void*)(gptr),             \
      (__attribute__((address_space(3))) void*)(lptr), 16, 0, 0)

__device__ __forceinline__ unsigned short f32_to_bf16(float f) {
  unsigned int u = __float_as_uint(f);
  u = u + 0x7fffu + ((u >> 16) & 1u);
  return (unsigned short)(u >> 16);
}
__device__ __forceinline__ unsigned int pack2(float a, float b) {
  return (unsigned int)f32_to_bf16(a) | ((unsigned int)f32_to_bf16(b) << 16);
}

// ws layout: [xp_t: BATCH*HP*WP*CIN bf16][slack 1024][wt: 9*COUT*CIN bf16]
// xp_t NHWC padded: xp_t[((b*58+i)*58+j)*128+ci] = x[b][ci][i-1][j-1] or 0.
// With BM=224 (4h x 56w) conv A-reads stay within [0,WP) in both h and w:
// no overrun, no garbage rows (SLACK retained but unused).

// Fused producers. Blocks [0,1856): pad+transpose one (b,i) row of xpt.
// Blocks [1856,2000): weight transpose (36864 uint4s, 144 blocks).
// pad LDS layout: tile2[w 0..57][ci], ci stored octet-interleaved:
// addr(w,ci) = w*192 + (ci>>3)*12 + (ci&7) floats. Octet stride 12 dwords
// -> pack-phase float4 reads are 2-way banked (free); write phase ~free.
__global__ void producers_kernel(const float* __restrict__ x,
                                 const float* __restrict__ wsrc,
                                 unsigned short* __restrict__ xpt,
                                 unsigned short* __restrict__ wt) {
  const int t = threadIdx.x;
  if (blockIdx.x >= BATCH * HP) {  // weight transpose part
    const int o8 = (blockIdx.x - BATCH * HP) * 256 + t;
    const int r = o8 >> 12;
    const int rem = o8 & 4095;
    const int co = rem >> 4;
    const int ci0 = (rem & 15) * 8;
    const float* s = wsrc + ((size_t)co * CIN + ci0) * 9 + r;
    uint4 pk;
    pk.x = pack2(s[0 * 9], s[1 * 9]);
    pk.y = pack2(s[2 * 9], s[3 * 9]);
    pk.z = pack2(s[4 * 9], s[5 * 9]);
    pk.w = pack2(s[6 * 9], s[7 * 9]);
    *(uint4*)(wt + (size_t)o8 * 8) = pk;
    return;
  }

  const int blk = blockIdx.x;  // b*58 + i
  const int b = blk / HP;
  const int i = blk - b * HP;
  unsigned short* dst = xpt + (size_t)blk * (WP * CIN);

  if (i == 0 || i == HP - 1) {  // pure pad row: store zeros, no LDS
    const uint4 z = {0, 0, 0, 0};
    for (int idx = t; idx < 928; idx += 256)
      *(uint4*)(dst + (size_t)idx * 8) = z;
    return;
  }

  __shared__ float tile2[58 * 192];  // [w][octet(ci)*12 + ci&7]
  // zero pad cols w=0 and w=57 (128 ci each)
  {
    const int ci = t & 127;
    const int base = (t < 128) ? 0 : 57 * 192;
    tile2[base + (ci >> 3) * 12 + (ci & 7)] = 0.0f;
  }
  // load phase: ci = t>>1, seg = t&1 covers w = 1+seg*28 .. 1+seg*28+27
  {
    const int ci = t >> 1;
    const int seg = t & 1;
    const int cio = (ci >> 3) * 12 + (ci & 7);
    const float* row =
        x + (((size_t)b * CIN + ci) * HH + (i - 1)) * WW + seg * 28;
#pragma unroll
    for (int q = 0; q < 7; ++q) {
      const float4 v = *(const float4*)(row + q * 4);
      const int w0 = 1 + seg * 28 + q * 4;
      tile2[(w0 + 0) * 192 + cio] = v.x;
      tile2[(w0 + 1) * 192 + cio] = v.y;
      tile2[(w0 + 2) * 192 + cio] = v.z;
      tile2[(w0 + 3) * 192 + cio] = v.w;
    }
  }
  __syncthreads();
  // pack: idx -> j = idx>>4, octet o = idx&15; vector float4 reads
  for (int idx = t; idx < 928; idx += 256) {
    const int j = idx >> 4;
    const float* src = &tile2[j * 192 + (idx & 15) * 12];
    const float4 a = *(const float4*)(src);
    const float4 c = *(const float4*)(src + 4);
    uint4 pk;
    pk.x = pack2(a.x, a.y);
    pk.y = pack2(a.z, a.w);
    pk.z = pack2(c.x, c.y);
    pk.w = pack2(c.z, c.w);
    *(uint4*)(dst + (size_t)idx * 8) = pk;
  }
}

// 224x256 tile (BM=224 = 4h x 56w: ZERO M-padding waste), 8 waves (2M x 4N),
// 112x64 out/wave, 512 threads. K = 1152 as 36 stages of K=32 through a
// ring of 4 LDS slots (30 KB each: A[224][32] + B[256][32]), depth-3
// prefetch via global_load_lds, counted s_waitcnt vmcnt(6) mid-loop
// (never 0), one raw s_barrier per stage, setprio around the MFMA cluster.
// Per-wave gload counts: waves 0-5 issue 4/stage (2A+2B), waves 6-7 issue
// 3/stage (1A+2B); vmcnt(6) publishes stage kk+1 for both (<=2 per-wave
// stages outstanding after the wait). Epilogue ni loop MUST stay unrolled
// (rule #20: runtime-indexed acc -> scratch, round-3 post-mortem).
__global__ __launch_bounds__(512, 2) void conv_gemm_kernel(
    const unsigned short* __restrict__ xpt,
    const unsigned short* __restrict__ wt,
    const float* __restrict__ bias,
    float* __restrict__ out) {
  // slot = 15360 shorts: A at [0,7168), B at [7168,15360). 4 slots = 120 KB.
  __shared__ __align__(16) uint32_t smem[30720];
  short* const S = (short*)smem;
  float* const ep = (float*)smem;  // epilogue alias [64 co'][228]

  // bijective XCD chunking: 448 % 8 == 0, each XCD gets 56 contiguous mt
  const int g = blockIdx.x;
  const int mt = (g & 7) * 56 + (g >> 3);  // 0..447
  const int b = mt / 14;
  const int h0 = (mt - b * 14) * 4;

  const int t = threadIdx.x;
  const int lane = t & 63;
  const int wv = t >> 6;      // 0..7
  const int mw = wv >> 2;     // 0..1
  const int nw = wv & 3;      // 0..3
  const int laneM = lane & 15;
  const int laneKg = lane >> 4;     // 0..3 (k-chunk group)
  const int rowreg = laneKg * 4;
  const bool hasA2 = (wv < 6);  // wave-uniform: A chunks 512..895

  // A staging: chunk u -> row mm = u>>2 (0..223 = hq*56+w), k-chunk p = u&3
  const unsigned short* agA[2];
  {
    const int mm1 = t >> 2;
    const int hq1 = mm1 / 56;
    const int w1 = mm1 - hq1 * 56;
    agA[0] = xpt + ((size_t)((b * HP + h0 + hq1) * WP + w1)) * CIN +
             (t & 3) * 8;
    const int mm2 = 128 + (t >> 2);
    const int hq2 = mm2 / 56;
    const int w2 = mm2 - hq2 * 56;
    agA[1] = xpt + ((size_t)((b * HP + h0 + hq2) * WP + w2)) * CIN +
             (t & 3) * 8;
  }
  // B staging: chunk u -> co = u>>2, p = u&3
  const unsigned short* bg[2];
  bg[0] = wt + (size_t)(t >> 2) * CIN + (t & 3) * 8;
  bg[1] = wt + (size_t)(128 + (t >> 2)) * CIN + (t & 3) * 8;

  const int dW = wv * 512;  // wave-uniform LDS dest offset (shorts)

  floatx4 acc[7][4] = {};

  // stage kk: tap r = kk>>2, ci-chunk = kk&3
  auto stageK = [&](int kk) {
    const int r = kk >> 2;
    const int dh = (r * 11) >> 5;  // r/3
    const int dw = r - dh * 3;
    const int aoff = (dh * WP + dw) * CIN + (kk & 3) * 32;
    const int boff = r * (COUT * CIN) + (kk & 3) * 32;
    short* const slot = S + (kk & 3) * 15360;
    GLOAD_LDS16(agA[0] + aoff, slot + dW);
    if (hasA2) GLOAD_LDS16(agA[1] + aoff, slot + 4096 + dW);
    GLOAD_LDS16(bg[0] + boff, slot + 7168 + dW);
    GLOAD_LDS16(bg[1] + boff, slot + 11264 + dW);
  };

  // prologue: stages 0..2 in flight; publish stage 0
  stageK(0);
  stageK(1);
  stageK(2);
  __builtin_amdgcn_sched_barrier(0);
  asm volatile("s_waitcnt vmcnt(6)" ::: "memory");
  __builtin_amdgcn_s_barrier();
  __builtin_amdgcn_sched_barrier(0);

  for (int kk = 0; kk < 36; ++kk) {
    const short* slot = S + (kk & 3) * 15360;
    short8 af[7], bf[4];
#pragma unroll
    for (int mi = 0; mi < 7; ++mi)
      af[mi] =
          *(const short8*)&slot[(mw * 112 + mi * 16 + laneM) * 32 + laneKg * 8];
#pragma unroll
    for (int ni = 0; ni < 4; ++ni)
      bf[ni] = *(const short8*)&slot[7168 +
                                     (nw * 64 + ni * 16 + laneM) * 32 +
                                     laneKg * 8];
    if (kk <= 32) stageK(kk + 3);  // depth-3 prefetch into slot (kk+3)&3
    __builtin_amdgcn_sched_barrier(0);
    __builtin_amdgcn_s_setprio(1);
#pragma unroll
    for (int mi = 0; mi < 7; ++mi)
#pragma unroll
      for (int ni = 0; ni < 4; ++ni)
        acc[mi][ni] = __builtin_amdgcn_mfma_f32_16x16x32_bf16(
            af[mi], bf[ni], acc[mi][ni], 0, 0, 0);
    __builtin_amdgcn_s_setprio(0);
    // publish stage kk+1: leave deeper prefetches in flight (counted waits)
    if (kk <= 32)
      asm volatile("s_waitcnt vmcnt(6)" ::: "memory");
    else if (kk == 33)
      asm volatile("s_waitcnt vmcnt(3)" ::: "memory");
    else if (kk == 34)
      asm volatile("s_waitcnt vmcnt(0)" ::: "memory");
    if (kk < 35) {
      __builtin_amdgcn_s_barrier();
      __builtin_amdgcn_sched_barrier(0);
    }
  }

  // Epilogue: 4 chunks (ni) of 64 co' x 224 m via LDS -> dense 224B rows.
  // acc[mi][ni] lane l: m = mw*112+mi*16+(l>>4)*4+reg (= hq*56 + w, all
  // valid), co = nw*64+ni*16+(l&15). ni loop MUST be unrolled (rule #20).
#pragma unroll
  for (int ni = 0; ni < 4; ++ni) {
    __syncthreads();
#pragma unroll
    for (int mi = 0; mi < 7; ++mi)
      *(float4*)&ep[(nw * 16 + laneM) * 228 + mw * 112 + mi * 16 + rowreg] =
          *(float4*)&acc[mi][ni];
    __syncthreads();
#pragma unroll
    for (int rr = 0; rr < 32; ++rr) {
      const int rid = wv * 32 + rr;
      const int cp = rid >> 2;    // co' = (nw<<4)|laneM of producer
      const int hq2 = rid & 3;    // h offset within tile
      const int co = (cp >> 4) * 64 + ni * 16 + (cp & 15);
      const float bv = bias[co];
      if (lane < WW) {
        out[(((size_t)b * COUT + co) * HH + h0 + hq2) * WW + lane] =
            ep[cp * 228 + hq2 * 56 + lane] + bv;
      }
    }
  }
}

// Fallback if ws is too small: correct but slow.
__global__ void naive_conv_kernel(const float* __restrict__ x,
                                  const float* __restrict__ wgt,
                                  const float* __restrict__ bias,
                                  float* __restrict__ out, long n) {
  long idx = (long)blockIdx.x * 256 + threadIdx.x;
  if (idx >= n) return;
  int w = (int)(idx % WW);
  long q = idx / WW;
  int h = (int)(q % HH);
  q /= HH;
  int co = (int)(q % COUT);
  int b = (int)(q / COUT);
  float s = bias[co];
  for (int ci = 0; ci < CIN; ++ci) {
    const float* xp = x + (((size_t)b * CIN + ci) * HH) * WW;
    const float* wp = wgt + ((size_t)co * CIN + ci) * 9;
    for (int dh = 0; dh < 3; ++dh) {
      int hh = h + dh - 1;
      if (hh < 0 || hh >= HH) continue;
      for (int dw = 0; dw < 3; ++dw) {
        int ww2 = w + dw - 1;
        if (ww2 < 0 || ww2 >= WW) continue;
        s += xp[hh * WW + ww2] * wp[dh * 3 + dw];
      }
    }
  }
  out[idx] = s;
}

extern "C" void kernel_launch(void* const* d_in, const int* in_sizes, int n_in,
                              void* d_out, int out_size, void* d_ws,
                              size_t ws_size, hipStream_t stream) {
  const float* x = (const float*)d_in[0];
  const float* wgt = (const float*)d_in[1];
  const float* bias = (const float*)d_in[2];
  float* out = (float*)d_out;

  const size_t XPT = (size_t)BATCH * HP * WP * CIN;  // 13,778,944
  const size_t SLACK = 1024;
  const size_t WT = (size_t)9 * COUT * CIN;  // 294,912
  const size_t need = (XPT + SLACK + WT) * sizeof(unsigned short);

  if (ws_size >= need) {
    unsigned short* xpt = (unsigned short*)d_ws;
    unsigned short* wtp = xpt + XPT + SLACK;
    hipLaunchKernelGGL(producers_kernel, dim3(BATCH * HP + 144), dim3(256), 0,
                       stream, x, wgt, xpt, wtp);
    hipLaunchKernelGGL(conv_gemm_kernel, dim3(448), dim3(512), 0, stream,
                       xpt, wtp, bias, out);
  } else {
    long n = (long)out_size;
    hipLaunchKernelGGL(naive_conv_kernel, dim3((unsigned)((n + 255) / 256)),
                       dim3(256), 0, stream, x, wgt, bias, out, n);
  }
}